// Round 2
// baseline (1571.397 us; speedup 1.0000x reference)
//
#include <hip/hip_runtime.h>

#define NQ     12
#define DIM    (1 << NQ)   // 4096 amplitudes
#define DEPTH  6

// ---------------------------------------------------------------------------
// Layout conventions (wire i <-> state-index bit (11-i); wire 0 = MSB):
//   Even ("A") sweep: lane t, register j  <->  amplitude q = (t<<6) | j
//   Odd  ("B") sweep: lane t, register j  <->  amplitude q = (j<<6) | t
// LDS holds one float array (re OR im) at a time in the swizzled layout
//   f(q) = q ^ ((q>>6)&63)   (keeps every b32 phase <=2-way bank aliased)
// The 11-CNOT chain maps index q -> C(q), bit k of C(q) = XOR of q bits k..11
// (suffix-xor). It is folded into the ODD sweep's store addresses: amp q is
// stored at f(C(q)), so CNOTs cost zero instructions.
//
// State lives in two 64-wide ext_vectors (SSA values -> guaranteed VGPRs;
// plain float[64] arrays tripped the promote-alloca size heuristic and went
// to scratch: 2.18 GB of HBM spill traffic in round 1).
// ---------------------------------------------------------------------------

typedef float f32x64 __attribute__((ext_vector_type(64)));

__device__ __host__ __forceinline__ constexpr int sufx6(int v) {
  int a = v ^ (v >> 1);
  a ^= a >> 2;
  a ^= a >> 4;
  return a & 63;
}
// float-index constant for CNOT-folded store (odd sweeps), register part:
// f(C(q)) = (SJ<<6) ^ SJ ^ ST(t) ^ (parity(j)?63:0), SJ = sufx6(j)
__device__ __host__ __forceinline__ constexpr int KCf(int j) {
  const int sj = sufx6(j);
  const int p  = __builtin_popcount((unsigned)j) & 1;
  return (sj << 6) ^ sj ^ (p ? 63 : 0);
}
// float-index constant for B-layout load: f((j<<6)|t) = ((j<<6)^j) ^ t
__device__ __host__ __forceinline__ constexpr int KBf(int j) { return (j << 6) ^ j; }

// Apply one fused 2x2 complex gate on local bit B of the 64-amp register tile.
// All indices compile-time -> pure VGPR, 16 FMA-class ops per pair.
template <int B>
__device__ __forceinline__ void gate6(f32x64 &re, f32x64 &im, float4 u0, float4 u1) {
  const float u00r = u0.x, u00i = u0.y, u01r = u0.z, u01i = u0.w;
  const float u10r = u1.x, u10i = u1.y, u11r = u1.z, u11i = u1.w;
#pragma unroll
  for (int m = 0; m < 32; ++m) {
    const int lo = m & ((1 << B) - 1);
    const int j0 = ((m >> B) << (B + 1)) | lo;  // local bit B == 0
    const int j1 = j0 | (1 << B);               // local bit B == 1
    const float ar = re[j0], ai = im[j0];
    const float br = re[j1], bi = im[j1];
    float nr0 = u00r * ar; nr0 = fmaf(-u00i, ai, nr0); nr0 = fmaf(u01r, br, nr0); nr0 = fmaf(-u01i, bi, nr0);
    float ni0 = u00r * ai; ni0 = fmaf( u00i, ar, ni0); ni0 = fmaf(u01r, bi, ni0); ni0 = fmaf( u01i, br, ni0);
    float nr1 = u10r * ar; nr1 = fmaf(-u10i, ai, nr1); nr1 = fmaf(u11r, br, nr1); nr1 = fmaf(-u11i, bi, nr1);
    float ni1 = u10r * ai; ni1 = fmaf( u10i, ar, ni1); ni1 = fmaf(u11r, bi, ni1); ni1 = fmaf( u11i, br, ni1);
    re[j0] = nr0; im[j0] = ni0;
    re[j1] = nr1; im[j1] = ni1;
  }
}

__global__ __launch_bounds__(64, 2) void qsim_kernel(const float* __restrict__ x,
                                                     const float* __restrict__ params,
                                                     float* __restrict__ out) {
  __shared__ float sm[DIM];               // 16 KiB transpose buffer (re or im per phase)
  __shared__ float uTab[DEPTH * NQ * 8];  // 72 fused 2x2 complex gates

  const int t = threadIdx.x;  // lane 0..63
  const int b = blockIdx.x;   // batch element

  // ---- precompute fused gates U = RX(p2) * RZ(p1) * RY(p0) into LDS ----
  for (int g = t; g < DEPTH * NQ; g += 64) {
    const int d = g / NQ, w = g % NQ;
    const float py = params[(d * NQ + w) * 3 + 0];
    const float pz = params[(d * NQ + w) * 3 + 1];
    const float px = params[(d * NQ + w) * 3 + 2];
    float sa, ca, sb, cb, sg, cg;
    __sincosf(py * 0.5f, &sa, &ca);
    __sincosf(pz * 0.5f, &sb, &cb);
    __sincosf(px * 0.5f, &sg, &cg);
    // RZ*RY entries: A=(ca*cb,-ca*sb) B=(-sa*cb,sa*sb) C=(sa*cb,sa*sb) D=(ca*cb,ca*sb)
    const float Ar = ca * cb, Ai = -ca * sb;
    const float Br = -sa * cb, Bi = sa * sb;
    const float Cr = sa * cb, Ci = sa * sb;
    const float Dr = ca * cb, Di = ca * sb;
    float* u = &uTab[g * 8];
    u[0] = cg * Ar + sg * Ci;   u[1] = cg * Ai - sg * Cr;   // u00
    u[2] = cg * Br + sg * Di;   u[3] = cg * Bi - sg * Dr;   // u01
    u[4] = sg * Ai + cg * Cr;   u[5] = -sg * Ar + cg * Ci;  // u10
    u[6] = sg * Bi + cg * Dr;   u[7] = -sg * Br + cg * Di;  // u11
  }

  // ---- product-state init (post RX-encoding), directly in A-layout regs ----
  f32x64 re, im;
  {
    float cs[NQ], sn[NQ];
#pragma unroll
    for (int i = 0; i < NQ; ++i) __sincosf(x[b * NQ + i] * 0.5f, &sn[i], &cs[i]);
    // high 6 bits (= lane t) are wires 0..5: wire i <-> t bit (5-i)
    float hm = 1.0f;
#pragma unroll
    for (int i = 0; i < 6; ++i) hm *= ((t >> (5 - i)) & 1) ? sn[i] : cs[i];
    // low 6 bits (= reg j) are wires 6..11: j bit bb <-> wire 11-bb; build products in-place
    re[0] = hm;
#pragma unroll
    for (int bb = 0; bb < 6; ++bb) {
#pragma unroll
      for (int j = 0; j < (1 << bb); ++j) {
        re[j | (1 << bb)] = re[j] * sn[11 - bb];
        re[j] = re[j] * cs[11 - bb];
      }
    }
    // amplitude = magnitude * (-i)^popcount(q)
    const int pt = __popc(t);
#pragma unroll
    for (int j = 0; j < 64; ++j) {
      const float m = re[j];
      const int k = (pt + __popc(j)) & 3;
      re[j] = (k & 1) ? 0.0f : ((k & 2) ? -m : m);
      im[j] = (k & 1) ? ((k & 2) ? m : -m) : 0.0f;
    }
  }

  __syncthreads();  // uTab ready

  const int KAf = (t << 6) ^ t;  // A store/load float-index base
  const int STf = sufx6(t);      // lane part of CNOT-folded store address

#pragma unroll 1
  for (int sw = 0; sw < 12; ++sw) {
    const int d = sw >> 1;
    const bool odd = sw & 1;

    // ---- 6 fused gates on the local bits ----
    // even sweep: local bit bb <-> global bit bb  <-> wire 11-bb
    // odd  sweep: local bit bb <-> global bit bb+6 <-> wire 5-bb
#define APPLY_GATE(BB)                                                        \
    {                                                                         \
      const int w = odd ? (5 - (BB)) : (11 - (BB));                           \
      const float4* uv = (const float4*)&uTab[(d * NQ + w) * 8];              \
      gate6<BB>(re, im, uv[0], uv[1]);                                        \
    }
    APPLY_GATE(0)
    APPLY_GATE(1)
    APPLY_GATE(2)
    APPLY_GATE(3)
    APPLY_GATE(4)
    APPLY_GATE(5)
#undef APPLY_GATE

    // ---- boundary: transpose A<->B layout through LDS (re phase, then im) ----
    // odd stores fold the full 11-CNOT chain of layer d into the address.
    if (odd) {
#pragma unroll
      for (int j = 0; j < 64; ++j) sm[STf ^ KCf(j)] = re[j];
    } else {
#pragma unroll
      for (int j = 0; j < 64; ++j) sm[KAf ^ j] = re[j];
    }
    __syncthreads();
    if (odd) {  // next sweep (or final output) uses A layout
#pragma unroll
      for (int j = 0; j < 64; ++j) re[j] = sm[KAf ^ j];
    } else {    // next sweep uses B layout
#pragma unroll
      for (int j = 0; j < 64; ++j) re[j] = sm[t ^ KBf(j)];
    }
    __syncthreads();
    if (odd) {
#pragma unroll
      for (int j = 0; j < 64; ++j) sm[STf ^ KCf(j)] = im[j];
    } else {
#pragma unroll
      for (int j = 0; j < 64; ++j) sm[KAf ^ j] = im[j];
    }
    __syncthreads();
    if (odd) {
#pragma unroll
      for (int j = 0; j < 64; ++j) im[j] = sm[KAf ^ j];
    } else {
#pragma unroll
      for (int j = 0; j < 64; ++j) im[j] = sm[t ^ KBf(j)];
    }
    __syncthreads();
  }

  // ---- output: <Z_w> = sum_q |amp(q)|^2 * (-1)^(bit(11-w) of q), A layout ----
  float tot = 0.0f;
  float sv[6] = {0.f, 0.f, 0.f, 0.f, 0.f, 0.f};  // signed sums over reg-index bits
#pragma unroll
  for (int j = 0; j < 64; ++j) {
    const float p = fmaf(re[j], re[j], im[j] * im[j]);
    tot += p;
#pragma unroll
    for (int bb = 0; bb < 6; ++bb) {
      if ((j >> bb) & 1) sv[bb] -= p; else sv[bb] += p;  // compile-time sign
    }
  }
  float v[12];
#pragma unroll
  for (int w = 0; w < 6; ++w) v[w] = ((t >> (5 - w)) & 1) ? -tot : tot;  // wires 0..5: lane bit
#pragma unroll
  for (int w = 6; w < 12; ++w) v[w] = sv[11 - w];                        // wires 6..11: reg bit
#pragma unroll
  for (int w = 0; w < 12; ++w) {
#pragma unroll
    for (int o = 32; o > 0; o >>= 1) v[w] += __shfl_xor(v[w], o);
  }
  if (t == 0) {
#pragma unroll
    for (int w = 0; w < 12; ++w) out[b * NQ + w] = v[w];
  }
}

extern "C" void kernel_launch(void* const* d_in, const int* in_sizes, int n_in,
                              void* d_out, int out_size, void* d_ws, size_t ws_size,
                              hipStream_t stream) {
  const float* x      = (const float*)d_in[0];
  const float* params = (const float*)d_in[1];
  float* out          = (float*)d_out;
  const int B = in_sizes[0] / NQ;  // 4096
  qsim_kernel<<<B, 64, 0, stream>>>(x, params, out);
}

// Round 3
// 255.114 us; speedup vs baseline: 6.1596x; 6.1596x over previous
//
#include <hip/hip_runtime.h>

#define NQ    12
#define DIM   4096      // 2^12 amplitudes
#define DEPTH 6
#define BLK   256       // one batch element per 256-thread block (4 waves)
#define RJ    16        // amplitudes per lane

// ---------------------------------------------------------------------------
// Wire i <-> state-index bit (11-i); wire 0 = MSB.
// Thread T = threadIdx.x (8 bits), per-lane register index j (4 bits).
// Layouts (which 4 state bits are register-local):
//   L0: q = (T<<4)|j                      local bits 0..3  = wires 8..11
//   L1: q = ((T>>4)<<8)|(j<<4)|(T&15)     local bits 4..7  = wires 4..7
//   L2: q = (j<<8)|T                      local bits 8..11 = wires 0..3
// LDS swizzle f(q) = q ^ ((q>>5)&31) is XOR-linear; every one of the six
// access patterns below is exactly 2-way bank aliased (free, m136).
// Addresses split as f(lane-part) ^ f(j-part): per-j parts are constexpr.
// The 11-CNOT chain is the GF(2)-linear suffix-xor C (bit k of C(q) = XOR of
// q bits k..11); it folds into the L2->L0 transpose store address (zero
// instructions): amp q is stored at f(C(q)).
// Round-1/2 lesson: 64 amps/lane spilled to scratch (2.8 GB HBM traffic);
// 16 amps/lane (32 floats) promotes to VGPRs reliably.
// ---------------------------------------------------------------------------

__device__ __forceinline__ int fsw(int q) { return q ^ ((q >> 5) & 31); }

__device__ __host__ __forceinline__ constexpr int sufxc(int v) {
  v ^= v >> 1; v ^= v >> 2; v ^= v >> 4; v ^= v >> 8; return v;
}
// per-j constants (constexpr -> folded after unroll)
__device__ __host__ __forceinline__ constexpr int K1c(int j) {  // f(j<<4)
  const int q = j << 4; return q ^ ((q >> 5) & 31);
}
__device__ __host__ __forceinline__ constexpr int K2c(int j) {  // f(j<<8)
  const int q = j << 8; return q ^ ((q >> 5) & 31);
}
__device__ __host__ __forceinline__ constexpr int KCc(int j) {  // f(C(j<<8))
  const int hi = (sufxc(j) & 15) << 8;
  const int lo = (__builtin_popcount((unsigned)j) & 1) ? 0xFF : 0;
  const int c  = hi | lo;
  return c ^ ((c >> 5) & 31);
}

// one fused 2x2 complex gate on local bit B of the 16-amp register tile
template <int B>
__device__ __forceinline__ void gate4(float (&re)[RJ], float (&im)[RJ],
                                      float4 u0, float4 u1) {
  const float u00r = u0.x, u00i = u0.y, u01r = u0.z, u01i = u0.w;
  const float u10r = u1.x, u10i = u1.y, u11r = u1.z, u11i = u1.w;
#pragma unroll
  for (int m = 0; m < RJ / 2; ++m) {
    const int lo = m & ((1 << B) - 1);
    const int j0 = ((m >> B) << (B + 1)) | lo;
    const int j1 = j0 | (1 << B);
    const float ar = re[j0], ai = im[j0];
    const float br = re[j1], bi = im[j1];
    float nr0 = u00r * ar; nr0 = fmaf(-u00i, ai, nr0); nr0 = fmaf(u01r, br, nr0); nr0 = fmaf(-u01i, bi, nr0);
    float ni0 = u00r * ai; ni0 = fmaf( u00i, ar, ni0); ni0 = fmaf(u01r, bi, ni0); ni0 = fmaf( u01i, br, ni0);
    float nr1 = u10r * ar; nr1 = fmaf(-u10i, ai, nr1); nr1 = fmaf(u11r, br, nr1); nr1 = fmaf(-u11i, bi, nr1);
    float ni1 = u10r * ai; ni1 = fmaf( u10i, ar, ni1); ni1 = fmaf(u11r, bi, ni1); ni1 = fmaf( u11i, br, ni1);
    re[j0] = nr0; im[j0] = ni0;
    re[j1] = nr1; im[j1] = ni1;
  }
}

__global__ __launch_bounds__(BLK) void qsim_kernel(const float* __restrict__ x,
                                                   const float* __restrict__ params,
                                                   float* __restrict__ out) {
  __shared__ float sm[2 * DIM];           // 32 KiB: re plane [0,4096), im plane [4096,8192)
  __shared__ float uTab[DEPTH * NQ * 8];  // 72 fused 2x2 complex gates

  const int T = threadIdx.x;
  const int b = blockIdx.x;

  // ---- fused gates U = RX(p2)*RZ(p1)*RY(p0) ----
  if (T < DEPTH * NQ) {
    const int d = T / NQ, w = T % NQ;
    const float py = params[T * 3 + 0];
    const float pz = params[T * 3 + 1];
    const float px = params[T * 3 + 2];
    float sa, ca, sb, cb, sg, cg;
    __sincosf(py * 0.5f, &sa, &ca);
    __sincosf(pz * 0.5f, &sb, &cb);
    __sincosf(px * 0.5f, &sg, &cg);
    const float Ar = ca * cb, Ai = -ca * sb;   // RZ*RY entries
    const float Br = -sa * cb, Bi = sa * sb;
    const float Cr = sa * cb, Ci = sa * sb;
    const float Dr = ca * cb, Di = ca * sb;
    float* u = &uTab[(d * NQ + w) * 8];
    u[0] = cg * Ar + sg * Ci;   u[1] = cg * Ai - sg * Cr;   // u00
    u[2] = cg * Br + sg * Di;   u[3] = cg * Bi - sg * Dr;   // u01
    u[4] = sg * Ai + cg * Cr;   u[5] = -sg * Ar + cg * Ci;  // u10
    u[6] = sg * Bi + cg * Dr;   u[7] = -sg * Br + cg * Di;  // u11
  }

  // ---- product-state init (RX encoding folded in), L0 layout ----
  float re[RJ], im[RJ];
  {
    float cs[NQ], sn[NQ];
#pragma unroll
    for (int i = 0; i < NQ; ++i) __sincosf(x[b * NQ + i] * 0.5f, &sn[i], &cs[i]);
    // wires 0..7 <-> T bits 7..0
    float hm = 1.0f;
#pragma unroll
    for (int i = 0; i < 8; ++i) hm *= ((T >> (7 - i)) & 1) ? sn[i] : cs[i];
    // wires 8..11 <-> j bits 3..0 (j bit bb <-> wire 11-bb)
    re[0] = hm;
#pragma unroll
    for (int bb = 0; bb < 4; ++bb) {
#pragma unroll
      for (int j = 0; j < (1 << bb); ++j) {
        re[j | (1 << bb)] = re[j] * sn[11 - bb];
        re[j] = re[j] * cs[11 - bb];
      }
    }
    // amplitude = magnitude * (-i)^popcount(q)
    const int pt = __popc(T);
#pragma unroll
    for (int j = 0; j < RJ; ++j) {
      const float m = re[j];
      const int k = (pt + __popc(j)) & 3;
      re[j] = (k & 1) ? 0.0f : ((k & 2) ? -m : m);
      im[j] = (k & 1) ? ((k & 2) ? m : -m) : 0.0f;
    }
  }

  __syncthreads();  // uTab ready

  // lane-scalar address bases (f of the lane part of q in each layout)
  const int A0 = fsw(T << 4);                              // L0
  const int B0 = fsw(((T >> 4) << 8) | (T & 15));          // L1
  const int C0 = fsw(T);                                   // L2
  const int D0 = fsw(sufxc(T) & 255);                      // L2 store with CNOT fold

#define SWEEP(D, WBASE)                                                       \
  {                                                                           \
    const float4* uv0 = (const float4*)&uTab[((D) * NQ + (WBASE)) * 8];       \
    gate4<0>(re, im, uv0[0], uv0[1]);                                         \
    const float4* uv1 = (const float4*)&uTab[((D) * NQ + (WBASE) - 1) * 8];   \
    gate4<1>(re, im, uv1[0], uv1[1]);                                         \
    const float4* uv2 = (const float4*)&uTab[((D) * NQ + (WBASE) - 2) * 8];   \
    gate4<2>(re, im, uv2[0], uv2[1]);                                         \
    const float4* uv3 = (const float4*)&uTab[((D) * NQ + (WBASE) - 3) * 8];   \
    gate4<3>(re, im, uv3[0], uv3[1]);                                         \
  }
#define ST_ALL(EXPR)                                                          \
  {                                                                           \
    _Pragma("unroll") for (int j = 0; j < RJ; ++j) {                          \
      const int a_ = (EXPR);                                                  \
      sm[a_] = re[j]; sm[DIM + a_] = im[j];                                   \
    }                                                                         \
  }
#define LD_ALL(EXPR)                                                          \
  {                                                                           \
    _Pragma("unroll") for (int j = 0; j < RJ; ++j) {                          \
      const int a_ = (EXPR);                                                  \
      re[j] = sm[a_]; im[j] = sm[DIM + a_];                                   \
    }                                                                         \
  }

#pragma unroll 1
  for (int d = 0; d < DEPTH; ++d) {
    SWEEP(d, 11)                    // wires 8..11 (local bit bb <-> wire 11-bb)
    ST_ALL(A0 ^ j) __syncthreads();
    LD_ALL(B0 ^ K1c(j)) __syncthreads();
    SWEEP(d, 7)                     // wires 4..7
    ST_ALL(B0 ^ K1c(j)) __syncthreads();
    LD_ALL(C0 ^ K2c(j)) __syncthreads();
    SWEEP(d, 3)                     // wires 0..3
    ST_ALL(D0 ^ KCc(j)) __syncthreads();   // CNOT chain folded into address
    LD_ALL(A0 ^ j) __syncthreads();
  }
#undef SWEEP
#undef ST_ALL
#undef LD_ALL

  // ---- output: <Z_w>, state in L0 layout ----
  float tot = 0.f, s0 = 0.f, s1 = 0.f, s2 = 0.f, s3 = 0.f;
#pragma unroll
  for (int j = 0; j < RJ; ++j) {
    const float p = fmaf(re[j], re[j], im[j] * im[j]);
    tot += p;
    s0 += (j & 1) ? -p : p;
    s1 += (j & 2) ? -p : p;
    s2 += (j & 4) ? -p : p;
    s3 += (j & 8) ? -p : p;
  }
  float v[NQ];
#pragma unroll
  for (int w = 0; w < 8; ++w) v[w] = ((T >> (7 - w)) & 1) ? -tot : tot;  // lane-bit wires
  v[8] = s3; v[9] = s2; v[10] = s1; v[11] = s0;                          // reg-bit wires
#pragma unroll
  for (int w = 0; w < NQ; ++w) {
#pragma unroll
    for (int o = 32; o > 0; o >>= 1) v[w] += __shfl_xor(v[w], o);
  }
  const int wv = T >> 6, lt = T & 63;
  if (lt == 0) {
#pragma unroll
    for (int w = 0; w < NQ; ++w) sm[w * 4 + wv] = v[w];  // sm reused post-barrier
  }
  __syncthreads();
  if (T < NQ) out[b * NQ + T] = (sm[T * 4 + 0] + sm[T * 4 + 1]) +
                                (sm[T * 4 + 2] + sm[T * 4 + 3]);
}

extern "C" void kernel_launch(void* const* d_in, const int* in_sizes, int n_in,
                              void* d_out, int out_size, void* d_ws, size_t ws_size,
                              hipStream_t stream) {
  const float* x      = (const float*)d_in[0];
  const float* params = (const float*)d_in[1];
  float* out          = (float*)d_out;
  const int B = in_sizes[0] / NQ;  // 4096
  qsim_kernel<<<B, BLK, 0, stream>>>(x, params, out);
}

// Round 4
// 242.461 us; speedup vs baseline: 6.4810x; 1.0522x over previous
//
#include <hip/hip_runtime.h>

#define NQ    12
#define DIM   4096      // 2^12 amplitudes
#define DEPTH 6
#define BLK   256       // one batch element per 256-thread block (4 waves)
#define RJ    16        // amplitudes per lane

// ---------------------------------------------------------------------------
// Wire i <-> state-index bit (11-i); wire 0 = MSB.
// Thread T (8 bits), per-lane register index j (4 bits). State held as
// interleaved complex f32x2 -> all gate math uses packed v_pk_fma_f32
// (2 packed FMA per complex MAC instead of 4 scalar FMA).
// Layouts (which 4 state bits are register-local):
//   L0: q = (T<<4)|j                      local bits 0..3  = wires 8..11
//   L1: q = ((T>>4)<<8)|(j<<4)|(T&15)     local bits 4..7  = wires 4..7
//   L2: q = (j<<8)|T                      local bits 8..11 = wires 0..3
// LDS holds 4096 8-byte words (f32x2), word index sigma(q) = q ^ ((q>>4)&15).
// Bank check (word-bank wb = word & 15, per 16-lane group):
//   L0 st/ld: wb = (t&15)^j          -> bijection in t (round-3 swizzle had
//   L1 st/ld: wb = (t&15)^j             2-way conflicts here: 12.66M cycles)
//   L2 ld:    wb = (t&15)^((t>>4)&3) -> bijection
//   CNOT st:  wb = triangular GF(2) map of t0..t3 -> bijection
// The 11-CNOT chain is the GF(2)-linear suffix-xor C (bit k = XOR of q bits
// k..11); folded into the L2->L0 transpose store address: amp q stored at
// sigma(C(q)) -> CNOTs cost zero instructions.
// Round-1/2 lesson: 64 amps/lane spilled to scratch; 16/lane (32 floats)
// promotes reliably (round 3: VGPR=64, hbm ~0.8 MB).
// ---------------------------------------------------------------------------

typedef float f32x2 __attribute__((ext_vector_type(2)));

__device__ __host__ __forceinline__ constexpr int sufxc(int v) {
  v ^= v >> 1; v ^= v >> 2; v ^= v >> 4; v ^= v >> 8; return v;
}
// per-j word-offset constants (constexpr -> folded after unroll)
__device__ __host__ __forceinline__ constexpr int K1w(int j) { return (j << 4) ^ j; }
__device__ __host__ __forceinline__ constexpr int K2w(int j) { return j << 8; }
__device__ __host__ __forceinline__ constexpr int KCw(int j) {  // sigma(C(j<<8))
  const int s4 = sufxc(j) & 15;
  const int p  = __builtin_popcount((unsigned)j) & 1;
  return (s4 << 8) | (p ? 0xF0 : 0);
}

__device__ __forceinline__ f32x2 pfma(f32x2 a, f32x2 b, f32x2 c) {
  return __builtin_elementwise_fma(a, b, c);
}

// one fused 2x2 complex gate on local bit B; 8 packed FMA-class ops per pair
template <int B>
__device__ __forceinline__ void gate4(f32x2 (&amp)[RJ], float4 u0, float4 u1) {
  const f32x2 r00 = {u0.x, u0.x}, mi00 = {-u0.y, u0.y};
  const f32x2 r01 = {u0.z, u0.z}, mi01 = {-u0.w, u0.w};
  const f32x2 r10 = {u1.x, u1.x}, mi10 = {-u1.y, u1.y};
  const f32x2 r11 = {u1.z, u1.z}, mi11 = {-u1.w, u1.w};
#pragma unroll
  for (int m = 0; m < RJ / 2; ++m) {
    const int lo = m & ((1 << B) - 1);
    const int j0 = ((m >> B) << (B + 1)) | lo;
    const int j1 = j0 | (1 << B);
    const f32x2 a = amp[j0], b = amp[j1];
    const f32x2 ax = a.yx, bx = b.yx;   // swap -> op_sel, free
    f32x2 n0 = r00 * a;
    n0 = pfma(mi00, ax, n0);
    n0 = pfma(r01, b, n0);
    n0 = pfma(mi01, bx, n0);
    f32x2 n1 = r10 * a;
    n1 = pfma(mi10, ax, n1);
    n1 = pfma(r11, b, n1);
    n1 = pfma(mi11, bx, n1);
    amp[j0] = n0; amp[j1] = n1;
  }
}

__global__ __launch_bounds__(BLK) void qsim_kernel(const float* __restrict__ x,
                                                   const float* __restrict__ params,
                                                   float* __restrict__ out) {
  __shared__ f32x2 sm2[DIM];              // 32 KiB transpose buffer (complex words)
  __shared__ float uTab[DEPTH * NQ * 8];  // 72 fused 2x2 complex gates

  const int T = threadIdx.x;
  const int b = blockIdx.x;

  // ---- fused gates U = RX(p2)*RZ(p1)*RY(p0) ----
  if (T < DEPTH * NQ) {
    const float py = params[T * 3 + 0];
    const float pz = params[T * 3 + 1];
    const float px = params[T * 3 + 2];
    float sa, ca, sb, cb, sg, cg;
    __sincosf(py * 0.5f, &sa, &ca);
    __sincosf(pz * 0.5f, &sb, &cb);
    __sincosf(px * 0.5f, &sg, &cg);
    const float Ar = ca * cb, Ai = -ca * sb;   // RZ*RY entries
    const float Br = -sa * cb, Bi = sa * sb;
    const float Cr = sa * cb, Ci = sa * sb;
    const float Dr = ca * cb, Di = ca * sb;
    float* u = &uTab[T * 8];
    u[0] = cg * Ar + sg * Ci;   u[1] = cg * Ai - sg * Cr;   // u00
    u[2] = cg * Br + sg * Di;   u[3] = cg * Bi - sg * Dr;   // u01
    u[4] = sg * Ai + cg * Cr;   u[5] = -sg * Ar + cg * Ci;  // u10
    u[6] = sg * Bi + cg * Dr;   u[7] = -sg * Br + cg * Di;  // u11
  }

  // ---- product-state init (RX encoding folded in), L0 layout ----
  f32x2 amp[RJ];
  {
    float cs[NQ], sn[NQ];
#pragma unroll
    for (int i = 0; i < NQ; ++i) __sincosf(x[b * NQ + i] * 0.5f, &sn[i], &cs[i]);
    // wires 0..7 <-> T bits 7..0
    float hm = 1.0f;
#pragma unroll
    for (int i = 0; i < 8; ++i) hm *= ((T >> (7 - i)) & 1) ? sn[i] : cs[i];
    // wires 8..11 <-> j bits 3..0 (j bit bb <-> wire 11-bb)
    float mag[RJ];
    mag[0] = hm;
#pragma unroll
    for (int bb = 0; bb < 4; ++bb) {
#pragma unroll
      for (int j = 0; j < (1 << bb); ++j) {
        mag[j | (1 << bb)] = mag[j] * sn[11 - bb];
        mag[j] = mag[j] * cs[11 - bb];
      }
    }
    // amplitude = magnitude * (-i)^popcount(q)
    const int pt = __popc(T);
#pragma unroll
    for (int j = 0; j < RJ; ++j) {
      const float m = mag[j];
      const int k = (pt + __popc(j)) & 3;
      const float rr = (k & 1) ? 0.0f : ((k & 2) ? -m : m);
      const float ii = (k & 1) ? ((k & 2) ? m : -m) : 0.0f;
      amp[j] = (f32x2){rr, ii};
    }
  }

  __syncthreads();  // uTab ready

  // lane word-address bases (sigma of the lane part of q in each layout)
  const int A0w = (T << 4) ^ (T & 15);                     // L0
  const int B0w = ((T >> 4) << 8) | (T & 15);              // L1
  const int C0w = T ^ ((T >> 4) & 15);                     // L2
  const int CT  = sufxc(T) & 255;
  const int D0w = CT ^ ((CT >> 4) & 15);                   // L2 store, CNOT-folded

#define SWEEP(D, WBASE)                                                       \
  {                                                                           \
    const float4* uv0 = (const float4*)&uTab[((D) * NQ + (WBASE)) * 8];       \
    gate4<0>(amp, uv0[0], uv0[1]);                                            \
    const float4* uv1 = (const float4*)&uTab[((D) * NQ + (WBASE) - 1) * 8];   \
    gate4<1>(amp, uv1[0], uv1[1]);                                            \
    const float4* uv2 = (const float4*)&uTab[((D) * NQ + (WBASE) - 2) * 8];   \
    gate4<2>(amp, uv2[0], uv2[1]);                                            \
    const float4* uv3 = (const float4*)&uTab[((D) * NQ + (WBASE) - 3) * 8];   \
    gate4<3>(amp, uv3[0], uv3[1]);                                            \
  }
#define ST_ALL(EXPR)                                                          \
  {                                                                           \
    _Pragma("unroll") for (int j = 0; j < RJ; ++j) { sm2[(EXPR)] = amp[j]; }  \
  }
#define LD_ALL(EXPR)                                                          \
  {                                                                           \
    _Pragma("unroll") for (int j = 0; j < RJ; ++j) { amp[j] = sm2[(EXPR)]; }  \
  }

#pragma unroll 1
  for (int d = 0; d < DEPTH; ++d) {
    SWEEP(d, 11)                    // wires 8..11 (local bit bb <-> wire 11-bb)
    ST_ALL(A0w ^ j) __syncthreads();
    LD_ALL(B0w ^ K1w(j)) __syncthreads();
    SWEEP(d, 7)                     // wires 4..7
    ST_ALL(B0w ^ K1w(j)) __syncthreads();
    LD_ALL(C0w ^ K2w(j)) __syncthreads();
    SWEEP(d, 3)                     // wires 0..3
    ST_ALL(D0w ^ KCw(j)) __syncthreads();   // CNOT chain folded into address
    LD_ALL(A0w ^ j) __syncthreads();
  }
#undef SWEEP
#undef ST_ALL
#undef LD_ALL

  // ---- output: <Z_w>, state in L0 layout ----
  float tot = 0.f, s0 = 0.f, s1 = 0.f, s2 = 0.f, s3 = 0.f;
#pragma unroll
  for (int j = 0; j < RJ; ++j) {
    const float p = fmaf(amp[j].x, amp[j].x, amp[j].y * amp[j].y);
    tot += p;
    s0 += (j & 1) ? -p : p;
    s1 += (j & 2) ? -p : p;
    s2 += (j & 4) ? -p : p;
    s3 += (j & 8) ? -p : p;
  }
  float v[NQ];
#pragma unroll
  for (int w = 0; w < 8; ++w) v[w] = ((T >> (7 - w)) & 1) ? -tot : tot;  // lane-bit wires
  v[8] = s3; v[9] = s2; v[10] = s1; v[11] = s0;                          // reg-bit wires
#pragma unroll
  for (int w = 0; w < NQ; ++w) {
#pragma unroll
    for (int o = 32; o > 0; o >>= 1) v[w] += __shfl_xor(v[w], o);
  }
  const int wv = T >> 6, lt = T & 63;
  float* smf = (float*)sm2;  // reuse post-barrier
  if (lt == 0) {
#pragma unroll
    for (int w = 0; w < NQ; ++w) smf[w * 4 + wv] = v[w];
  }
  __syncthreads();
  if (T < NQ) out[b * NQ + T] = (smf[T * 4 + 0] + smf[T * 4 + 1]) +
                                (smf[T * 4 + 2] + smf[T * 4 + 3]);
}

extern "C" void kernel_launch(void* const* d_in, const int* in_sizes, int n_in,
                              void* d_out, int out_size, void* d_ws, size_t ws_size,
                              hipStream_t stream) {
  const float* x      = (const float*)d_in[0];
  const float* params = (const float*)d_in[1];
  float* out          = (float*)d_out;
  const int B = in_sizes[0] / NQ;  // 4096
  qsim_kernel<<<B, BLK, 0, stream>>>(x, params, out);
}

// Round 5
// 238.219 us; speedup vs baseline: 6.5964x; 1.0178x over previous
//
#include <hip/hip_runtime.h>

#define NQ    12
#define DIM   4096      // 2^12 amplitudes
#define DEPTH 6
#define BLK   256       // one batch element per 256-thread block (4 waves)
#define RJ    16        // amplitudes per lane

// ---------------------------------------------------------------------------
// Wire i <-> state-index bit (11-i); wire 0 = MSB.
// Thread T (8 bits), per-lane register index j (4 bits). State held as
// interleaved complex f32x2 (packed-FMA friendly).
// Layouts (which 4 state bits are register-local):
//   L0: q = (T<<4)|j                      local bits 0..3  = wires 8..11
//   L1: q = ((T>>4)<<8)|(j<<4)|(T&15)     local bits 4..7  = wires 4..7
//   L2: q = (j<<8)|T                      local bits 8..11 = wires 0..3
// LDS: 4096 8-byte words (f32x2), word index sigma(q) = q ^ ((q>>4)&15).
// b64 accesses are inherently 2-way bank-phased (benign: same bytes/cycle as
// clean b32; measured 6.37M "conflicts" = exactly this, ~5% LDS-pipe).
// The 11-CNOT chain (GF(2)-linear suffix-xor C) folds into the L2->L0 store
// address: amp q stored at sigma(C(q)) -> zero instructions.
//
// Barrier schedule (round-5): hazard analysis shows
//   P1 (L0->L1): thread-/wave-private slices -> NO barrier (lgkmcnt only)
//   P2 store: wave-private -> no pre-barrier; P2 ST->LD cross-wave: barrier
//   pre-CNOT-store: WAR vs other waves' P2 loads: barrier
//   CNOT ST->LD: cross-wave RAW: barrier
// => 3 barriers/layer (was 6). Gates are precomputed by a tiny prep kernel
// into d_ws and read via block-uniform global loads (no uTab LDS, no
// per-block sincos, no init barrier).
// ---------------------------------------------------------------------------

typedef float f32x2 __attribute__((ext_vector_type(2)));

__device__ __host__ __forceinline__ constexpr int sufxc(int v) {
  v ^= v >> 1; v ^= v >> 2; v ^= v >> 4; v ^= v >> 8; return v;
}
// per-j word-offset constants (constexpr -> folded after unroll)
__device__ __host__ __forceinline__ constexpr int K1w(int j) { return (j << 4) ^ j; }
__device__ __host__ __forceinline__ constexpr int K2w(int j) { return j << 8; }
__device__ __host__ __forceinline__ constexpr int KCw(int j) {  // sigma(C(j<<8))
  const int s4 = sufxc(j) & 15;
  const int p  = __builtin_popcount((unsigned)j) & 1;
  return (s4 << 8) | (p ? 0xF0 : 0);
}

__device__ __forceinline__ f32x2 pfma(f32x2 a, f32x2 b, f32x2 c) {
  return __builtin_elementwise_fma(a, b, c);
}

// one fused 2x2 complex gate on local bit B; 8 packed FMA-class ops per pair
template <int B>
__device__ __forceinline__ void gate4(f32x2 (&amp)[RJ], float4 u0, float4 u1) {
  const f32x2 r00 = {u0.x, u0.x}, mi00 = {-u0.y, u0.y};
  const f32x2 r01 = {u0.z, u0.z}, mi01 = {-u0.w, u0.w};
  const f32x2 r10 = {u1.x, u1.x}, mi10 = {-u1.y, u1.y};
  const f32x2 r11 = {u1.z, u1.z}, mi11 = {-u1.w, u1.w};
#pragma unroll
  for (int m = 0; m < RJ / 2; ++m) {
    const int lo = m & ((1 << B) - 1);
    const int j0 = ((m >> B) << (B + 1)) | lo;
    const int j1 = j0 | (1 << B);
    const f32x2 a = amp[j0], b = amp[j1];
    const f32x2 ax = a.yx, bx = b.yx;   // component swap (op_sel / reg-rename)
    f32x2 n0 = r00 * a;
    n0 = pfma(mi00, ax, n0);
    n0 = pfma(r01, b, n0);
    n0 = pfma(mi01, bx, n0);
    f32x2 n1 = r10 * a;
    n1 = pfma(mi10, ax, n1);
    n1 = pfma(r11, b, n1);
    n1 = pfma(mi11, bx, n1);
    amp[j0] = n0; amp[j1] = n1;
  }
}

// ---- prep kernel: fused gates U = RX(p2)*RZ(p1)*RY(p0) -> d_ws (72 x 8 f32)
__global__ void gate_prep(const float* __restrict__ params, float* __restrict__ gt) {
  const int T = threadIdx.x;
  if (T >= DEPTH * NQ) return;
  const float py = params[T * 3 + 0];
  const float pz = params[T * 3 + 1];
  const float px = params[T * 3 + 2];
  float sa, ca, sb, cb, sg, cg;
  __sincosf(py * 0.5f, &sa, &ca);
  __sincosf(pz * 0.5f, &sb, &cb);
  __sincosf(px * 0.5f, &sg, &cg);
  const float Ar = ca * cb, Ai = -ca * sb;   // RZ*RY entries
  const float Br = -sa * cb, Bi = sa * sb;
  const float Cr = sa * cb, Ci = sa * sb;
  const float Dr = ca * cb, Di = ca * sb;
  float* u = &gt[T * 8];
  u[0] = cg * Ar + sg * Ci;   u[1] = cg * Ai - sg * Cr;   // u00
  u[2] = cg * Br + sg * Di;   u[3] = cg * Bi - sg * Dr;   // u01
  u[4] = sg * Ai + cg * Cr;   u[5] = -sg * Ar + cg * Ci;  // u10
  u[6] = sg * Bi + cg * Dr;   u[7] = -sg * Br + cg * Di;  // u11
}

__global__ __launch_bounds__(BLK) void qsim_kernel(const float* __restrict__ x,
                                                   const float* __restrict__ gt,
                                                   float* __restrict__ out) {
  __shared__ f32x2 sm2[DIM];              // 32 KiB transpose buffer

  const int T = threadIdx.x;
  const int b = blockIdx.x;

  // ---- product-state init (RX encoding folded in), L0 layout ----
  f32x2 amp[RJ];
  {
    float cs[NQ], sn[NQ];
#pragma unroll
    for (int i = 0; i < NQ; ++i) __sincosf(x[b * NQ + i] * 0.5f, &sn[i], &cs[i]);
    // wires 0..7 <-> T bits 7..0
    float hm = 1.0f;
#pragma unroll
    for (int i = 0; i < 8; ++i) hm *= ((T >> (7 - i)) & 1) ? sn[i] : cs[i];
    // wires 8..11 <-> j bits 3..0 (j bit bb <-> wire 11-bb)
    float mag[RJ];
    mag[0] = hm;
#pragma unroll
    for (int bb = 0; bb < 4; ++bb) {
#pragma unroll
      for (int j = 0; j < (1 << bb); ++j) {
        mag[j | (1 << bb)] = mag[j] * sn[11 - bb];
        mag[j] = mag[j] * cs[11 - bb];
      }
    }
    // amplitude = magnitude * (-i)^popcount(q)
    const int pt = __popc(T);
#pragma unroll
    for (int j = 0; j < RJ; ++j) {
      const float m = mag[j];
      const int k = (pt + __popc(j)) & 3;
      const float rr = (k & 1) ? 0.0f : ((k & 2) ? -m : m);
      const float ii = (k & 1) ? ((k & 2) ? m : -m) : 0.0f;
      amp[j] = (f32x2){rr, ii};
    }
  }

  // lane word-address bases (sigma of the lane part of q in each layout)
  const int A0w = (T << 4) ^ (T & 15);                     // L0
  const int B0w = ((T >> 4) << 8) | (T & 15);              // L1
  const int C0w = T ^ ((T >> 4) & 15);                     // L2
  const int CT  = sufxc(T) & 255;
  const int D0w = CT ^ ((CT >> 4) & 15);                   // L2 store, CNOT-folded

#define SWEEP(D, WBASE)                                                       \
  {                                                                           \
    const float4* uv0 = (const float4*)&gt[((D) * NQ + (WBASE)) * 8];         \
    gate4<0>(amp, uv0[0], uv0[1]);                                            \
    const float4* uv1 = (const float4*)&gt[((D) * NQ + (WBASE) - 1) * 8];     \
    gate4<1>(amp, uv1[0], uv1[1]);                                            \
    const float4* uv2 = (const float4*)&gt[((D) * NQ + (WBASE) - 2) * 8];     \
    gate4<2>(amp, uv2[0], uv2[1]);                                            \
    const float4* uv3 = (const float4*)&gt[((D) * NQ + (WBASE) - 3) * 8];     \
    gate4<3>(amp, uv3[0], uv3[1]);                                            \
  }
#define ST_ALL(EXPR)                                                          \
  {                                                                           \
    _Pragma("unroll") for (int j = 0; j < RJ; ++j) { sm2[(EXPR)] = amp[j]; }  \
  }
#define LD_ALL(EXPR)                                                          \
  {                                                                           \
    _Pragma("unroll") for (int j = 0; j < RJ; ++j) { amp[j] = sm2[(EXPR)]; }  \
  }

#pragma unroll 1
  for (int d = 0; d < DEPTH; ++d) {
    SWEEP(d, 11)                    // wires 8..11 (local bit bb <-> wire 11-bb)
    ST_ALL(A0w ^ j)                 // L0 store: thread-private slice
    LD_ALL(B0w ^ K1w(j))            // L1 load: own-wave slices (lgkmcnt only)
    SWEEP(d, 7)                     // wires 4..7
    ST_ALL(B0w ^ K1w(j))            // L1 store: wave-private (no pre-barrier)
    __syncthreads();                // (a) RAW: cross-wave L2 loads
    LD_ALL(C0w ^ K2w(j))
    SWEEP(d, 3)                     // wires 0..3
    __syncthreads();                // (b) WAR: all P2 loads done before CNOT stores
    ST_ALL(D0w ^ KCw(j))            // CNOT chain folded into address
    __syncthreads();                // (c) RAW: cross-wave L0 loads
    LD_ALL(A0w ^ j)
  }
#undef SWEEP
#undef ST_ALL
#undef LD_ALL

  // ---- output: <Z_w>, state in L0 layout ----
  float tot = 0.f, s0 = 0.f, s1 = 0.f, s2 = 0.f, s3 = 0.f;
#pragma unroll
  for (int j = 0; j < RJ; ++j) {
    const float p = fmaf(amp[j].x, amp[j].x, amp[j].y * amp[j].y);
    tot += p;
    s0 += (j & 1) ? -p : p;
    s1 += (j & 2) ? -p : p;
    s2 += (j & 4) ? -p : p;
    s3 += (j & 8) ? -p : p;
  }
  float v[NQ];
#pragma unroll
  for (int w = 0; w < 8; ++w) v[w] = ((T >> (7 - w)) & 1) ? -tot : tot;  // lane-bit wires
  v[8] = s3; v[9] = s2; v[10] = s1; v[11] = s0;                          // reg-bit wires
#pragma unroll
  for (int w = 0; w < NQ; ++w) {
#pragma unroll
    for (int o = 32; o > 0; o >>= 1) v[w] += __shfl_xor(v[w], o);
  }
  __syncthreads();  // WAR: all lanes' final LDS loads done before smf reuse
  const int wv = T >> 6, lt = T & 63;
  float* smf = (float*)sm2;
  if (lt == 0) {
#pragma unroll
    for (int w = 0; w < NQ; ++w) smf[w * 4 + wv] = v[w];
  }
  __syncthreads();
  if (T < NQ) out[b * NQ + T] = (smf[T * 4 + 0] + smf[T * 4 + 1]) +
                                (smf[T * 4 + 2] + smf[T * 4 + 3]);
}

extern "C" void kernel_launch(void* const* d_in, const int* in_sizes, int n_in,
                              void* d_out, int out_size, void* d_ws, size_t ws_size,
                              hipStream_t stream) {
  const float* x      = (const float*)d_in[0];
  const float* params = (const float*)d_in[1];
  float* out          = (float*)d_out;
  float* gt           = (float*)d_ws;   // 72 gates x 8 floats = 2304 B
  const int B = in_sizes[0] / NQ;       // 4096
  gate_prep<<<1, 128, 0, stream>>>(params, gt);
  qsim_kernel<<<B, BLK, 0, stream>>>(x, gt, out);
}